// Round 8
// baseline (312.905 us; speedup 1.0000x reference)
//
#include <hip/hip_runtime.h>
#include <stdint.h>

typedef __attribute__((ext_vector_type(8))) short short8;
typedef __attribute__((ext_vector_type(4))) float f32x4;

// ---- byte offsets into d_ws (max end 74,054,656 B; ws >= 75.7 MB proven R1-R3) ----
#define B_STATS  60416ull      // 4*256 fp32 = 4096
#define B_E2     1178624ull    // 64*13*128*32 bf16 = 6815744
#define B_XB     7994368ull    // 2048*3328 bf16 = 13631488
#define B_MAIN   21625856ull   // 2048*256*25 bf16 = 26214400
#define B_RES    47840256ull   // 2048*256*25 bf16 = 26214400

#define NTV 51200.0f

__device__ __forceinline__ unsigned short f2bf(float f) {
    unsigned u = __float_as_uint(f);
    return (unsigned short)((u + 0x7fffu + ((u >> 16) & 1u)) >> 16);
}
__device__ __forceinline__ float bf2f(unsigned s) { return __uint_as_float(s << 16); }

__device__ __forceinline__ float wave_sum(float v) {
#pragma unroll
    for (int m = 1; m < 64; m <<= 1) v += __shfl_xor(v, m, 64);
    return v;
}

// KA: E2 prep with inline BnA + stats zeroing. Grid 129.
__global__ __launch_bounds__(256) void k_prepE(const int* __restrict__ hop,
                                               const float* __restrict__ emb,
                                               const float* __restrict__ A,
                                               const float* __restrict__ w_block,
                                               unsigned short* __restrict__ E2,
                                               float* __restrict__ stats) {
    int bid = blockIdx.x, tid = threadIdx.x;
    if (bid == 128) {
#pragma unroll
        for (int i = 0; i < 4; i++) stats[i*256 + tid] = 0.f;
        return;
    }
    __shared__ float bl[1875];     // [k3][v][w]
    __shared__ float wl[192];      // [k3][o][c]
    __shared__ float invn[150];    // invb[75], inva[75] : [k3][w]
    int half = bid & 1, og = (bid >> 1) & 7, h = bid >> 4;

    if (tid < 75) {
        int k3 = tid / 25, w = tid - k3*25;
        int g = k3*8 + h;
        float nb = 0.f, na = 0.f;
        for (int v = 0; v < 25; v++) {
            float e = emb[g*12 + hop[v*25 + w]];
            nb += e*e;
            float a = A[((size_t)g*25 + v)*25 + w];
            na += a*a;
        }
        invn[tid]      = 1.f / (sqrtf(nb) + 1e-4f);
        invn[75 + tid] = 1.f / (sqrtf(na) + 1e-4f);
    }
    if (tid < 192) {
        int k3 = tid >> 6, o = (tid >> 4) & 3, c = tid & 15;
        wl[tid] = w_block[(k3*256 + h*32 + og*4 + o)*16 + c];
    }
    __syncthreads();
    for (int i = tid; i < 1875; i += 256) {
        int k3 = i / 625, vw = i - k3*625, v = vw / 25, w = vw - v*25;
        int g = k3*8 + h;
        float e = emb[g*12 + hop[v*25 + w]];
        float a = A[((size_t)g*25 + v)*25 + w];
        bl[i] = e*invn[k3*25 + w] + a*invn[75 + k3*25 + w];
    }
    __syncthreads();

    unsigned short* dst = E2 + (size_t)(h*8 + og)*53248;
    int e0 = half * 26624;
    for (int e = e0 + tid; e < e0 + 26624; e += 256) {
        int kc = e >> 12;
        int n  = (e >> 5) & 127;
        int kk = e & 31;
        int k  = kc*32 + kk;
        int o  = n >> 5, w = n & 31;
        float val = 0.f;
        if (k < 400 && w < 25) {
            int c = k / 25, v = k - c*25;
            val = wl[0*64 + o*16 + c] * bl[0*625 + v*25 + w]
                + wl[1*64 + o*16 + c] * bl[1*625 + v*25 + w]
                + wl[2*64 + o*16 + c] * bl[2*625 + v*25 + w];
        }
        dst[e] = f2bf(val);
    }
}

// KB: xprep with LDS bounce -> contiguous uint4 stores. Grid 2048.
__global__ __launch_bounds__(256) void k_xprep(const float* __restrict__ x,
                                               unsigned short* __restrict__ xb) {
    __shared__ __align__(16) unsigned short row[3328];
    int b = blockIdx.x;
    int n_ = b >> 7, t_ = b & 127;
    int tid = threadIdx.x;
    const float* xs = x + ((size_t)n_*128*128 + t_)*25;   // + c*3200 + v
    for (int idx = tid; idx < 3200; idx += 256) {
        int c = idx / 25, v = idx - c*25;
        row[(c >> 4)*416 + (c & 15)*25 + v] = f2bf(xs[(size_t)c*3200 + v]);
    }
    if (tid < 128) row[(tid >> 4)*416 + 400 + (tid & 15)] = 0;
    __syncthreads();
    const uint4* s = (const uint4*)row;
    uint4* d = (uint4*)(xb + (size_t)b*3328);
    for (int i = tid; i < 416; i += 256) d[i] = s[i];
}

// KC: residual GEMM (flipped), standalone. Grid 800 = 400 mt x 2 nt.
// M = oc (A = res_w), N = m2=(b,v) (B = x, coalesced float4), K = 128.
__global__ __launch_bounds__(256) void k_res(const float* __restrict__ x,
                                             const float* __restrict__ res_w,
                                             unsigned short* __restrict__ resp,
                                             float* __restrict__ stats) {
    __shared__ unsigned short Al[128*40];
    __shared__ unsigned short Bl[128*40];
    int bid = blockIdx.x, tid = threadIdx.x;
    int nt = bid & 1, mt = bid >> 1;
    int lane = tid & 63, wave = tid >> 6;
    int wm = wave >> 1, wn = wave & 1;
    int lane15 = lane & 15, quad = lane >> 4;

    int srow = tid >> 1, shalf = tid & 1;
    int m2grp = tid & 31, ckk = tid >> 5;
    int n_ = mt / 25;
    int rembase = (mt - n_*25)*128 + m2grp*4;
    const float* xn = x + (size_t)n_*128*3200;

    f32x4 acc[4][4] = {};

    for (int kc = 0; kc < 4; kc++) {
        {
            const float4* s = (const float4*)(res_w + (size_t)(nt*128 + srow)*128 + kc*32 + shalf*16);
            float4 f0 = s[0], f1 = s[1], f2 = s[2], f3 = s[3];
            float fv[16] = {f0.x,f0.y,f0.z,f0.w, f1.x,f1.y,f1.z,f1.w,
                            f2.x,f2.y,f2.z,f2.w, f3.x,f3.y,f3.z,f3.w};
            unsigned pk[8];
#pragma unroll
            for (int q = 0; q < 8; q++)
                pk[q] = (unsigned)f2bf(fv[2*q]) | ((unsigned)f2bf(fv[2*q+1]) << 16);
            *(uint4*)&Al[srow*40 + shalf*16]     = make_uint4(pk[0],pk[1],pk[2],pk[3]);
            *(uint4*)&Al[srow*40 + shalf*16 + 8] = make_uint4(pk[4],pk[5],pk[6],pk[7]);
        }
        {
            float4 xv[4];
#pragma unroll
            for (int dk = 0; dk < 4; dk++) {
                int c = kc*32 + ckk*4 + dk;
                xv[dk] = *(const float4*)(xn + (size_t)c*3200 + rembase);
            }
#pragma unroll
            for (int r = 0; r < 4; r++) {
                float b0 = (r==0?xv[0].x:r==1?xv[0].y:r==2?xv[0].z:xv[0].w);
                float b1 = (r==0?xv[1].x:r==1?xv[1].y:r==2?xv[1].z:xv[1].w);
                float b2 = (r==0?xv[2].x:r==1?xv[2].y:r==2?xv[2].z:xv[2].w);
                float b3 = (r==0?xv[3].x:r==1?xv[3].y:r==2?xv[3].z:xv[3].w);
                unsigned p0 = (unsigned)f2bf(b0) | ((unsigned)f2bf(b1) << 16);
                unsigned p1 = (unsigned)f2bf(b2) | ((unsigned)f2bf(b3) << 16);
                *(uint2*)&Bl[(m2grp*4 + r)*40 + ckk*4] = make_uint2(p0, p1);
            }
        }
        __syncthreads();

        short8 af[4], bf[4];
#pragma unroll
        for (int i = 0; i < 4; i++) {
            af[i] = *(const short8*)&Al[(wm*64 + i*16 + lane15)*40 + quad*8];
            bf[i] = *(const short8*)&Bl[(wn*64 + i*16 + lane15)*40 + quad*8];
        }
#pragma unroll
        for (int i = 0; i < 4; i++)
#pragma unroll
            for (int j = 0; j < 4; j++)
                acc[i][j] = __builtin_amdgcn_mfma_f32_16x16x32_bf16(af[i], bf[j], acc[i][j], 0, 0, 0);
        __syncthreads();
    }

#pragma unroll
    for (int i = 0; i < 4; i++) {
#pragma unroll
        for (int r = 0; r < 4; r++) {
            int oc = nt*128 + wm*64 + i*16 + quad*4 + r;
            float sv = 0.f, sq = 0.f;
#pragma unroll
            for (int j = 0; j < 4; j++) {
                float val = acc[i][j][r];
                int M2 = mt*128 + wn*64 + j*16 + lane15;
                int b = M2 / 25, v = M2 - b*25;
                resp[(size_t)(b*256 + oc)*25 + v] = f2bf(val);
                sv += val;
                sq = fmaf(val, val, sq);
            }
            sv += __shfl_xor(sv, 1, 64); sv += __shfl_xor(sv, 2, 64);
            sv += __shfl_xor(sv, 4, 64); sv += __shfl_xor(sv, 8, 64);
            sq += __shfl_xor(sq, 1, 64); sq += __shfl_xor(sq, 2, 64);
            sq += __shfl_xor(sq, 4, 64); sq += __shfl_xor(sq, 8, 64);
            if (lane15 == 0) {
                atomicAdd(&stats[512 + oc], sv);
                atomicAdd(&stats[768 + oc], sq);
            }
        }
    }
}

// KD: main GEMM. Grid 1024, mt fastest (XCD A-locality). Double-buffered, padded LDS.
__global__ __launch_bounds__(256) void k_gc(const unsigned short* __restrict__ xb,
                                            const unsigned short* __restrict__ E2,
                                            unsigned short* __restrict__ mainp,
                                            float* __restrict__ stats) {
    __shared__ unsigned short Al[2][128*40];
    __shared__ unsigned short Bl[2][128*40];
    int bid = blockIdx.x;
    int mt = bid & 15, hog = bid >> 4;
    int h = hog >> 3, og = hog & 7;
    int tid = threadIdx.x;
    int lane = tid & 63, wave = tid >> 6;
    int wm = wave >> 1, wn = wave & 1;
    int lane15 = lane & 15, quad = lane >> 4;

    int srow = tid >> 1, shalf = tid & 1;
    const size_t abase = (size_t)(mt*128 + srow)*3328 + h*416 + shalf*16;
    const size_t bbase = (size_t)hog*53248 + tid*16;
    int sof = srow*40 + shalf*16;

    {
        const uint4* sa = (const uint4*)(xb + abase);
        uint4 a0 = sa[0], a1 = sa[1];
        *(uint4*)&Al[0][sof] = a0; *(uint4*)&Al[0][sof + 8] = a1;
        const uint4* sb = (const uint4*)(E2 + bbase);
        uint4 b0 = sb[0], b1 = sb[1];
        *(uint4*)&Bl[0][sof] = b0; *(uint4*)&Bl[0][sof + 8] = b1;
    }
    __syncthreads();

    f32x4 acc[4][4] = {};

    for (int kc = 0; kc < 13; kc++) {
        int cur = kc & 1, nxt = cur ^ 1;
        uint4 a0, a1, b0, b1;
        bool hasNext = (kc < 12);
        if (hasNext) {
            const uint4* sa = (const uint4*)(xb + abase + (kc + 1)*32);
            a0 = sa[0]; a1 = sa[1];
            const uint4* sb = (const uint4*)(E2 + bbase + (size_t)(kc + 1)*4096);
            b0 = sb[0]; b1 = sb[1];
        }
        short8 af[4], bf[4];
#pragma unroll
        for (int i = 0; i < 4; i++) {
            af[i] = *(const short8*)&Al[cur][(wm*64 + i*16 + lane15)*40 + quad*8];
            bf[i] = *(const short8*)&Bl[cur][(wn*64 + i*16 + lane15)*40 + quad*8];
        }
#pragma unroll
        for (int i = 0; i < 4; i++)
#pragma unroll
            for (int j = 0; j < 4; j++)
                acc[i][j] = __builtin_amdgcn_mfma_f32_16x16x32_bf16(af[i], bf[j], acc[i][j], 0, 0, 0);
        if (hasNext) {
            *(uint4*)&Al[nxt][sof] = a0; *(uint4*)&Al[nxt][sof + 8] = a1;
            *(uint4*)&Bl[nxt][sof] = b0; *(uint4*)&Bl[nxt][sof + 8] = b1;
        }
        __syncthreads();
    }

    float s1[2] = {0.f, 0.f}, s2[2] = {0.f, 0.f};
#pragma unroll
    for (int j = 0; j < 4; j++) {
        int w = (j & 1)*16 + lane15;
        int p = j >> 1;
        if (w < 25) {
            int oc = h*32 + og*4 + wn*2 + p;
#pragma unroll
            for (int i = 0; i < 4; i++) {
                int mb = mt*128 + wm*64 + i*16 + quad*4;
#pragma unroll
                for (int r = 0; r < 4; r++) {
                    float val = acc[i][j][r];
                    mainp[(size_t)((mb + r)*256 + oc)*25 + w] = f2bf(val);
                    s1[p] += val;
                    s2[p] = fmaf(val, val, s2[p]);
                }
            }
        }
    }
#pragma unroll
    for (int p = 0; p < 2; p++) {
        float a = wave_sum(s1[p]);
        float b = wave_sum(s2[p]);
        if (lane == 0) {
            int oc = h*32 + og*4 + wn*2 + p;
            atomicAdd(&stats[oc], a);
            atomicAdd(&stats[256 + oc], b);
        }
    }
}

// KE: out = relu(BN1(main) + BN2(res)); LDS-bounced coalesced reads.
__global__ __launch_bounds__(256) void k_final(const float* __restrict__ bn_g,
                                               const float* __restrict__ bn_b,
                                               const float* __restrict__ rbn_g,
                                               const float* __restrict__ rbn_b,
                                               const float* __restrict__ stats,
                                               const unsigned short* __restrict__ mainp,
                                               const unsigned short* __restrict__ resp,
                                               float* __restrict__ out) {
    __shared__ __align__(16) unsigned short ml[6400];
    __shared__ __align__(16) unsigned short rl[6400];
    int b = blockIdx.x;
    int n_ = b >> 7, t_ = b & 127;
    int tid = threadIdx.x;

    const uint4* msrc = (const uint4*)(mainp + (size_t)b*6400);
    const uint4* rsrc = (const uint4*)(resp  + (size_t)b*6400);
    for (int idx = tid; idx < 800; idx += 256) {
        ((uint4*)ml)[idx] = msrc[idx];
        ((uint4*)rl)[idx] = rsrc[idx];
    }
    __syncthreads();

    int oc = tid;
    const float inv = 1.f / NTV;
    float s1 = stats[oc],       s2 = stats[256 + oc];
    float r1 = stats[512 + oc], r2 = stats[768 + oc];
    float mm = s1*inv, vm = s2*inv - mm*mm;
    float mr = r1*inv, vr = r2*inv - mr*mr;
    float a1 = bn_g[oc]  * rsqrtf(vm + 1e-5f); float c1 = bn_b[oc]  - a1*mm;
    float a2 = rbn_g[oc] * rsqrtf(vr + 1e-5f); float c2 = rbn_b[oc] - a2*mr;

    float* op = out + ((size_t)(n_*256 + oc)*128 + t_)*25;
#pragma unroll
    for (int w = 0; w < 25; w++) {
        float val = fmaf(a1, bf2f(ml[oc*25 + w]), c1) + fmaf(a2, bf2f(rl[oc*25 + w]), c2);
        op[w] = fmaxf(val, 0.f);
    }
}

extern "C" void kernel_launch(void* const* d_in, const int* in_sizes, int n_in,
                              void* d_out, int out_size, void* d_ws, size_t ws_size,
                              hipStream_t stream) {
    const float* x        = (const float*)d_in[0];
    const int*   hop      = (const int*)  d_in[1];
    const float* emb      = (const float*)d_in[2];
    const float* A        = (const float*)d_in[3];
    const float* w_block  = (const float*)d_in[4];
    // d_in[5] b_block, d_in[9] res_b: per-channel biases cancel under batchnorm.
    const float* bn_g     = (const float*)d_in[6];
    const float* bn_b     = (const float*)d_in[7];
    const float* res_w    = (const float*)d_in[8];
    const float* rbn_g    = (const float*)d_in[10];
    const float* rbn_b    = (const float*)d_in[11];
    float* out = (float*)d_out;

    char* ws = (char*)d_ws;
    float*          stats  = (float*)(ws + B_STATS);
    unsigned short* E2     = (unsigned short*)(ws + B_E2);
    unsigned short* xb     = (unsigned short*)(ws + B_XB);
    unsigned short* mainp  = (unsigned short*)(ws + B_MAIN);
    unsigned short* resp   = (unsigned short*)(ws + B_RES);

    k_prepE <<<129,  256, 0, stream>>>(hop, emb, A, w_block, E2, stats);
    k_xprep <<<2048, 256, 0, stream>>>(x, xb);
    k_res   <<<800,  256, 0, stream>>>(x, res_w, resp, stats);
    k_gc    <<<1024, 256, 0, stream>>>(xb, E2, mainp, stats);
    k_final <<<2048, 256, 0, stream>>>(bn_g, bn_b, rbn_g, rbn_b, stats, mainp, resp, out);
}

// Round 9
// 245.896 us; speedup vs baseline: 1.2725x; 1.2725x over previous
//
#include <hip/hip_runtime.h>
#include <stdint.h>

typedef __attribute__((ext_vector_type(8))) short short8;
typedef __attribute__((ext_vector_type(4))) float f32x4;

// ---- byte offsets into d_ws (max end 74,054,656 B; ws >= 75.7 MB proven R1-R3) ----
#define B_STATS  60416ull      // 4*256 fp32 = 4096
#define B_RESW2  64512ull      // 256*128 bf16 = 65536
#define B_E2     1178624ull    // 64*13*128*32 bf16 = 6815744
#define B_XB     7994368ull    // 2048*3328 bf16 = 13631488
#define B_MAIN   21625856ull   // 2048*256*25 bf16 = 26214400
#define B_RES    47840256ull   // 2048*256*25 bf16 = 26214400

#define NTV 51200.0f

__device__ __forceinline__ unsigned short f2bf(float f) {
    unsigned u = __float_as_uint(f);
    return (unsigned short)((u + 0x7fffu + ((u >> 16) & 1u)) >> 16);
}
__device__ __forceinline__ float bf2f(unsigned s) { return __uint_as_float(s << 16); }

__device__ __forceinline__ float wave_sum(float v) {
#pragma unroll
    for (int m = 1; m < 64; m <<= 1) v += __shfl_xor(v, m, 64);
    return v;
}

// KA: E2 prep (inline BnA) + stats zeroing + resw2 bf16 pack. Grid 137.
__global__ __launch_bounds__(256) void k_prepE(const int* __restrict__ hop,
                                               const float* __restrict__ emb,
                                               const float* __restrict__ A,
                                               const float* __restrict__ w_block,
                                               const float* __restrict__ res_w,
                                               unsigned short* __restrict__ E2,
                                               float* __restrict__ stats,
                                               unsigned short* __restrict__ resw2) {
    int bid = blockIdx.x, tid = threadIdx.x;
    if (bid >= 128) {
        if (bid == 136) {
#pragma unroll
            for (int i = 0; i < 4; i++) stats[i*256 + tid] = 0.f;
        } else {
            int base = (bid - 128) * 4096 + tid * 16;
#pragma unroll
            for (int j = 0; j < 16; j++) resw2[base + j] = f2bf(res_w[base + j]);
        }
        return;
    }
    __shared__ float bl[1875];     // [k3][v][w]
    __shared__ float wl[192];      // [k3][o][c]
    __shared__ float invn[150];    // invb[75], inva[75] : [k3][w]
    int half = bid & 1, og = (bid >> 1) & 7, h = bid >> 4;

    if (tid < 75) {
        int k3 = tid / 25, w = tid - k3*25;
        int g = k3*8 + h;
        float nb = 0.f, na = 0.f;
        for (int v = 0; v < 25; v++) {
            float e = emb[g*12 + hop[v*25 + w]];
            nb += e*e;
            float a = A[((size_t)g*25 + v)*25 + w];
            na += a*a;
        }
        invn[tid]      = 1.f / (sqrtf(nb) + 1e-4f);
        invn[75 + tid] = 1.f / (sqrtf(na) + 1e-4f);
    }
    if (tid < 192) {
        int k3 = tid >> 6, o = (tid >> 4) & 3, c = tid & 15;
        wl[tid] = w_block[(k3*256 + h*32 + og*4 + o)*16 + c];
    }
    __syncthreads();
    for (int i = tid; i < 1875; i += 256) {
        int k3 = i / 625, vw = i - k3*625, v = vw / 25, w = vw - v*25;
        int g = k3*8 + h;
        float e = emb[g*12 + hop[v*25 + w]];
        float a = A[((size_t)g*25 + v)*25 + w];
        bl[i] = e*invn[k3*25 + w] + a*invn[75 + k3*25 + w];
    }
    __syncthreads();

    unsigned short* dst = E2 + (size_t)(h*8 + og)*53248;
    int e0 = half * 26624;
    for (int e = e0 + tid; e < e0 + 26624; e += 256) {
        int kc = e >> 12;
        int n  = (e >> 5) & 127;
        int kk = e & 31;
        int k  = kc*32 + kk;
        int o  = n >> 5, w = n & 31;
        float val = 0.f;
        if (k < 400 && w < 25) {
            int c = k / 25, v = k - c*25;
            val = wl[0*64 + o*16 + c] * bl[0*625 + v*25 + w]
                + wl[1*64 + o*16 + c] * bl[1*625 + v*25 + w]
                + wl[2*64 + o*16 + c] * bl[2*625 + v*25 + w];
        }
        dst[e] = f2bf(val);
    }
}

// KB: xprep with LDS bounce -> contiguous uint4 stores. Grid 2048.
__global__ __launch_bounds__(256) void k_xprep(const float* __restrict__ x,
                                               unsigned short* __restrict__ xb) {
    __shared__ __align__(16) unsigned short row[3328];
    int b = blockIdx.x;
    int n_ = b >> 7, t_ = b & 127;
    int tid = threadIdx.x;
    const float* xs = x + ((size_t)n_*128*128 + t_)*25;   // + c*3200 + v
    for (int idx = tid; idx < 3200; idx += 256) {
        int c = idx / 25, v = idx - c*25;
        row[(c >> 4)*416 + (c & 15)*25 + v] = f2bf(xs[(size_t)c*3200 + v]);
    }
    if (tid < 128) row[(tid >> 4)*416 + 400 + (tid & 15)] = 0;
    __syncthreads();
    const uint4* s = (const uint4*)row;
    uint4* d = (uint4*)(xb + (size_t)b*3328);
    for (int i = tid; i < 416; i += 256) d[i] = s[i];
}

// KC: residual GEMM, R6 orientation. Grid 800 = 400 mt x 2 nt.
// M = m2=(b,v) (A = x, strided scalar->bf16), N = oc (B = resw2), K = 128.
__global__ __launch_bounds__(256) void k_res(const float* __restrict__ x,
                                             const unsigned short* __restrict__ resw2,
                                             unsigned short* __restrict__ resp,
                                             float* __restrict__ stats) {
    __shared__ unsigned short Al[128*40];
    __shared__ unsigned short Bl[128*40];
    int bid = blockIdx.x, tid = threadIdx.x;
    int nt = bid & 1, mt = bid >> 1;
    int lane = tid & 63, wave = tid >> 6;
    int wm = wave >> 1, wn = wave & 1;
    int lane15 = lane & 15, quad = lane >> 4;

    int m2row = tid >> 1, shalf = tid & 1;
    int m2 = mt*128 + m2row;
    int bb = m2 / 25, vv = m2 - bb*25;
    int n_ = bb >> 7, t_ = bb & 127;
    const float* xbase = x + ((size_t)n_*128*128 + t_)*25 + vv;  // + c*3200

    f32x4 acc[4][4] = {};

    for (int kc = 0; kc < 4; kc++) {
        {
            unsigned short tmp[16];
            int c0 = kc*32 + shalf*16;
#pragma unroll
            for (int j = 0; j < 16; j++)
                tmp[j] = f2bf(xbase[(size_t)(c0 + j)*3200]);
            unsigned pk[8];
#pragma unroll
            for (int q = 0; q < 8; q++)
                pk[q] = (unsigned)tmp[2*q] | ((unsigned)tmp[2*q+1] << 16);
            *(uint4*)&Al[m2row*40 + shalf*16]     = make_uint4(pk[0], pk[1], pk[2], pk[3]);
            *(uint4*)&Al[m2row*40 + shalf*16 + 8] = make_uint4(pk[4], pk[5], pk[6], pk[7]);
        }
        {
            const uint4* s = (const uint4*)(resw2 + (size_t)(nt*128 + m2row)*128 + kc*32 + shalf*16);
            uint4 b0 = s[0], b1 = s[1];
            *(uint4*)&Bl[m2row*40 + shalf*16]     = b0;
            *(uint4*)&Bl[m2row*40 + shalf*16 + 8] = b1;
        }
        __syncthreads();

        short8 af[4], bf[4];
#pragma unroll
        for (int i = 0; i < 4; i++) {
            af[i] = *(const short8*)&Al[(wm*64 + i*16 + lane15)*40 + quad*8];
            bf[i] = *(const short8*)&Bl[(wn*64 + i*16 + lane15)*40 + quad*8];
        }
#pragma unroll
        for (int i = 0; i < 4; i++)
#pragma unroll
            for (int j = 0; j < 4; j++)
                acc[i][j] = __builtin_amdgcn_mfma_f32_16x16x32_bf16(af[i], bf[j], acc[i][j], 0, 0, 0);
        __syncthreads();
    }

    // epilogue + per-oc stats (oc = nt*128 + wn*64 + j*16 + lane15: 16 lanes/line)
#pragma unroll
    for (int j = 0; j < 4; j++) {
        int oc = nt*128 + wn*64 + j*16 + lane15;
        float s1 = 0.f, s2 = 0.f;
#pragma unroll
        for (int i = 0; i < 4; i++) {
            int m2b = mt*128 + wm*64 + i*16 + quad*4;
#pragma unroll
            for (int r = 0; r < 4; r++) {
                float val = acc[i][j][r];
                int m2e = m2b + r;
                int b = m2e / 25, v = m2e - b*25;
                resp[(size_t)(b*256 + oc)*25 + v] = f2bf(val);
                s1 += val;
                s2 = fmaf(val, val, s2);
            }
        }
        s1 += __shfl_xor(s1, 16, 64); s1 += __shfl_xor(s1, 32, 64);
        s2 += __shfl_xor(s2, 16, 64); s2 += __shfl_xor(s2, 32, 64);
        if (quad == 0) {
            atomicAdd(&stats[512 + oc], s1);
            atomicAdd(&stats[768 + oc], s2);
        }
    }
}

// KD: main GEMM. Grid 1024, mt fastest (XCD A-locality). Double-buffered, padded LDS.
__global__ __launch_bounds__(256) void k_gc(const unsigned short* __restrict__ xb,
                                            const unsigned short* __restrict__ E2,
                                            unsigned short* __restrict__ mainp,
                                            float* __restrict__ stats) {
    __shared__ unsigned short Al[2][128*40];
    __shared__ unsigned short Bl[2][128*40];
    int bid = blockIdx.x;
    int mt = bid & 15, hog = bid >> 4;
    int h = hog >> 3, og = hog & 7;
    int tid = threadIdx.x;
    int lane = tid & 63, wave = tid >> 6;
    int wm = wave >> 1, wn = wave & 1;
    int lane15 = lane & 15, quad = lane >> 4;

    int srow = tid >> 1, shalf = tid & 1;
    const size_t abase = (size_t)(mt*128 + srow)*3328 + h*416 + shalf*16;
    const size_t bbase = (size_t)hog*53248 + tid*16;
    int sof = srow*40 + shalf*16;

    {
        const uint4* sa = (const uint4*)(xb + abase);
        uint4 a0 = sa[0], a1 = sa[1];
        *(uint4*)&Al[0][sof] = a0; *(uint4*)&Al[0][sof + 8] = a1;
        const uint4* sb = (const uint4*)(E2 + bbase);
        uint4 b0 = sb[0], b1 = sb[1];
        *(uint4*)&Bl[0][sof] = b0; *(uint4*)&Bl[0][sof + 8] = b1;
    }
    __syncthreads();

    f32x4 acc[4][4] = {};

    for (int kc = 0; kc < 13; kc++) {
        int cur = kc & 1, nxt = cur ^ 1;
        uint4 a0, a1, b0, b1;
        bool hasNext = (kc < 12);
        if (hasNext) {
            const uint4* sa = (const uint4*)(xb + abase + (kc + 1)*32);
            a0 = sa[0]; a1 = sa[1];
            const uint4* sb = (const uint4*)(E2 + bbase + (size_t)(kc + 1)*4096);
            b0 = sb[0]; b1 = sb[1];
        }
        short8 af[4], bf[4];
#pragma unroll
        for (int i = 0; i < 4; i++) {
            af[i] = *(const short8*)&Al[cur][(wm*64 + i*16 + lane15)*40 + quad*8];
            bf[i] = *(const short8*)&Bl[cur][(wn*64 + i*16 + lane15)*40 + quad*8];
        }
#pragma unroll
        for (int i = 0; i < 4; i++)
#pragma unroll
            for (int j = 0; j < 4; j++)
                acc[i][j] = __builtin_amdgcn_mfma_f32_16x16x32_bf16(af[i], bf[j], acc[i][j], 0, 0, 0);
        if (hasNext) {
            *(uint4*)&Al[nxt][sof] = a0; *(uint4*)&Al[nxt][sof + 8] = a1;
            *(uint4*)&Bl[nxt][sof] = b0; *(uint4*)&Bl[nxt][sof + 8] = b1;
        }
        __syncthreads();
    }

    float s1[2] = {0.f, 0.f}, s2[2] = {0.f, 0.f};
#pragma unroll
    for (int j = 0; j < 4; j++) {
        int w = (j & 1)*16 + lane15;
        int p = j >> 1;
        if (w < 25) {
            int oc = h*32 + og*4 + wn*2 + p;
#pragma unroll
            for (int i = 0; i < 4; i++) {
                int mb = mt*128 + wm*64 + i*16 + quad*4;
#pragma unroll
                for (int r = 0; r < 4; r++) {
                    float val = acc[i][j][r];
                    mainp[(size_t)((mb + r)*256 + oc)*25 + w] = f2bf(val);
                    s1[p] += val;
                    s2[p] = fmaf(val, val, s2[p]);
                }
            }
        }
    }
#pragma unroll
    for (int p = 0; p < 2; p++) {
        float a = wave_sum(s1[p]);
        float b = wave_sum(s2[p]);
        if (lane == 0) {
            int oc = h*32 + og*4 + wn*2 + p;
            atomicAdd(&stats[oc], a);
            atomicAdd(&stats[256 + oc], b);
        }
    }
}

// KE: out = relu(BN1(main) + BN2(res)); LDS-bounced coalesced reads.
__global__ __launch_bounds__(256) void k_final(const float* __restrict__ bn_g,
                                               const float* __restrict__ bn_b,
                                               const float* __restrict__ rbn_g,
                                               const float* __restrict__ rbn_b,
                                               const float* __restrict__ stats,
                                               const unsigned short* __restrict__ mainp,
                                               const unsigned short* __restrict__ resp,
                                               float* __restrict__ out) {
    __shared__ __align__(16) unsigned short ml[6400];
    __shared__ __align__(16) unsigned short rl[6400];
    int b = blockIdx.x;
    int n_ = b >> 7, t_ = b & 127;
    int tid = threadIdx.x;

    const uint4* msrc = (const uint4*)(mainp + (size_t)b*6400);
    const uint4* rsrc = (const uint4*)(resp  + (size_t)b*6400);
    for (int idx = tid; idx < 800; idx += 256) {
        ((uint4*)ml)[idx] = msrc[idx];
        ((uint4*)rl)[idx] = rsrc[idx];
    }
    __syncthreads();

    int oc = tid;
    const float inv = 1.f / NTV;
    float s1 = stats[oc],       s2 = stats[256 + oc];
    float r1 = stats[512 + oc], r2 = stats[768 + oc];
    float mm = s1*inv, vm = s2*inv - mm*mm;
    float mr = r1*inv, vr = r2*inv - mr*mr;
    float a1 = bn_g[oc]  * rsqrtf(vm + 1e-5f); float c1 = bn_b[oc]  - a1*mm;
    float a2 = rbn_g[oc] * rsqrtf(vr + 1e-5f); float c2 = rbn_b[oc] - a2*mr;

    float* op = out + ((size_t)(n_*256 + oc)*128 + t_)*25;
#pragma unroll
    for (int w = 0; w < 25; w++) {
        float val = fmaf(a1, bf2f(ml[oc*25 + w]), c1) + fmaf(a2, bf2f(rl[oc*25 + w]), c2);
        op[w] = fmaxf(val, 0.f);
    }
}

extern "C" void kernel_launch(void* const* d_in, const int* in_sizes, int n_in,
                              void* d_out, int out_size, void* d_ws, size_t ws_size,
                              hipStream_t stream) {
    const float* x        = (const float*)d_in[0];
    const int*   hop      = (const int*)  d_in[1];
    const float* emb      = (const float*)d_in[2];
    const float* A        = (const float*)d_in[3];
    const float* w_block  = (const float*)d_in[4];
    // d_in[5] b_block, d_in[9] res_b: per-channel biases cancel under batchnorm.
    const float* bn_g     = (const float*)d_in[6];
    const float* bn_b     = (const float*)d_in[7];
    const float* res_w    = (const float*)d_in[8];
    const float* rbn_g    = (const float*)d_in[10];
    const float* rbn_b    = (const float*)d_in[11];
    float* out = (float*)d_out;

    char* ws = (char*)d_ws;
    float*          stats  = (float*)(ws + B_STATS);
    unsigned short* resw2  = (unsigned short*)(ws + B_RESW2);
    unsigned short* E2     = (unsigned short*)(ws + B_E2);
    unsigned short* xb     = (unsigned short*)(ws + B_XB);
    unsigned short* mainp  = (unsigned short*)(ws + B_MAIN);
    unsigned short* resp   = (unsigned short*)(ws + B_RES);

    k_prepE <<<137,  256, 0, stream>>>(hop, emb, A, w_block, res_w, E2, stats, resw2);
    k_xprep <<<2048, 256, 0, stream>>>(x, xb);
    k_res   <<<800,  256, 0, stream>>>(x, resw2, resp, stats);
    k_gc    <<<1024, 256, 0, stream>>>(xb, E2, mainp, stats);
    k_final <<<2048, 256, 0, stream>>>(bn_g, bn_b, rbn_g, rbn_b, stats, mainp, resp, out);
}